// Round 7
// baseline (709.367 us; speedup 1.0000x reference)
//
#include <hip/hip_runtime.h>

#define DM 768
#define DS 16
#define SEQ 2048
#define BATCH 2
#define MROWS (BATCH*SEQ)   // 4096
#define MR8 (MROWS+8)       // padded t-stride
#define N_UV (2*DM)         // 1536
#define N_BC (DM*DS)        // 12288
#define NGRP (BATCH*DM/4)   // 384 scan wave-groups
#define SUBMAX 32

typedef _Float16 half8 __attribute__((ext_vector_type(8)));
typedef float floatx4 __attribute__((ext_vector_type(4)));

static __device__ __forceinline__ unsigned short f2h(float f) {
  _Float16 h = (_Float16)f;
  return __builtin_bit_cast(unsigned short, h);
}
static __device__ __forceinline__ float h2f(unsigned short u) {
  return (float)__builtin_bit_cast(_Float16, u);
}
static __device__ __forceinline__ float softplus_f(float x) {
  return (x > 20.f) ? x : log1pf(__expf(x));
}
// async global->LDS, 16B per lane; LDS dest = l + lane*16 (l wave-uniform)
static __device__ __forceinline__ void async_cp16(const unsigned short* g,
                                                  unsigned short* l) {
  __builtin_amdgcn_global_load_lds(
      (const __attribute__((address_space(1))) void*)g,
      (__attribute__((address_space(3))) void*)l, 16, 0, 0);
}
// sum across each 16-lane row via DPP row_ror (pure VALU, no LDS pipe)
static __device__ __forceinline__ float row_reduce16(float v) {
  int x;
  x = __builtin_amdgcn_update_dpp(0, __builtin_bit_cast(int, v), 0x128, 0xf, 0xf, true);
  v += __builtin_bit_cast(float, x);
  x = __builtin_amdgcn_update_dpp(0, __builtin_bit_cast(int, v), 0x124, 0xf, 0xf, true);
  v += __builtin_bit_cast(float, x);
  x = __builtin_amdgcn_update_dpp(0, __builtin_bit_cast(int, v), 0x122, 0xf, 0xf, true);
  v += __builtin_bit_cast(float, x);
  x = __builtin_amdgcn_update_dpp(0, __builtin_bit_cast(int, v), 0x121, 0xf, 0xf, true);
  v += __builtin_bit_cast(float, x);
  return v;
}

// elementwise fp32 -> fp16 ; n divisible by 1024
__global__ void convert_f2h(const float* __restrict__ in,
                            unsigned short* __restrict__ out, int n) {
  int i = (blockIdx.x * blockDim.x + threadIdx.x) * 4;
  if (i >= n) return;
  float4 f = *(const float4*)(in + i);
  ushort4 h;
  h.x = f2h(f.x); h.y = f2h(f.y); h.z = f2h(f.z); h.w = f2h(f.w);
  *(ushort4*)(out + i) = h;
}

// All 5 weight transposes in one launch (z selects). W [768][N] f32 -> WT [N][768] f16.
__global__ void transpose_w5(const float* __restrict__ W0, const float* __restrict__ W1,
                             const float* __restrict__ W2, const float* __restrict__ W3,
                             const float* __restrict__ W4,
                             unsigned short* __restrict__ T0, unsigned short* __restrict__ T1,
                             unsigned short* __restrict__ T2, unsigned short* __restrict__ T3,
                             unsigned short* __restrict__ T4,
                             int N0, int N1, int N2, int N3, int N4) {
  const float* W; unsigned short* WT; int N;
  switch (blockIdx.z) {
    case 0: W = W0; WT = T0; N = N0; break;
    case 1: W = W1; WT = T1; N = N1; break;
    case 2: W = W2; WT = T2; N = N2; break;
    case 3: W = W3; WT = T3; N = N3; break;
    default: W = W4; WT = T4; N = N4; break;
  }
  int n0 = blockIdx.x * 32;
  if (n0 >= N) return;
  int k0 = blockIdx.y * 32;
  __shared__ float tile[32][33];
  int tx = threadIdx.x, ty = threadIdx.y;   // (32,8)
#pragma unroll
  for (int i = 0; i < 32; i += 8)
    tile[ty + i][tx] = W[(size_t)(k0 + ty + i) * N + (n0 + tx)];
  __syncthreads();
  int kp = tx & 15, half = tx >> 4;
#pragma unroll
  for (int i = 0; i < 2; i++) {
    int nl = ty + half * 8 + i * 16;
    unsigned int pk = (unsigned int)f2h(tile[2 * kp][nl]) |
                      ((unsigned int)f2h(tile[2 * kp + 1][nl]) << 16);
    *(unsigned int*)&WT[(size_t)(n0 + nl) * DM + k0 + 2 * kp] = pk;
  }
}

// fp16 [T][src_ld] -> [C][dst_ld] tile transpose
__global__ void transpose_h(const unsigned short* __restrict__ src, int src_ld,
                            unsigned short* __restrict__ dst, int dst_ld) {
  __shared__ __align__(16) unsigned short tile[64][72];
  int t0 = blockIdx.x * 64, c0 = blockIdx.y * 64;
  int tid = threadIdx.x;
  int lr = tid >> 3, lc = (tid & 7) * 8;
#pragma unroll
  for (int rr = 0; rr < 64; rr += 32)
    *(uint4*)&tile[rr + lr][lc] = *(const uint4*)&src[(size_t)(t0 + rr + lr) * src_ld + c0 + lc];
  __syncthreads();
  int sc = tid >> 3, st = (tid & 7) * 8;
#pragma unroll
  for (int cc = 0; cc < 64; cc += 32) {
    union { unsigned short h[8]; uint4 v; } pk;
#pragma unroll
    for (int i = 0; i < 8; i++) pk.h[i] = tile[st + i][cc + sc];
    *(uint4*)&dst[(size_t)(c0 + cc + sc) * dst_ld + t0 + st] = pk.v;
  }
}

// D = A[g(M)][K] @ BT[N][K]^T + bias.
// TRANS=0: out[m][n] (OUTH: fp16 else fp32). TRANS=1: out [n][ldT] fp16 via LDS shuffle.
// A-row remap g(m) = (m/TCa)*bstride + row0 + (m%TCa); gridDim.z picks (BT,bias,out).
// 128x128 tile, BK=32, global_load_lds staging, XOR-swizzled LDS.
template<int ACT, int OUTH, int TRANS>
__global__ __launch_bounds__(256)
void gemm_f16(const unsigned short* __restrict__ A,
              const unsigned short* __restrict__ BT0,
              const unsigned short* __restrict__ BT1,
              const float* __restrict__ bias0,
              const float* __restrict__ bias1,
              void* __restrict__ Cout0,
              void* __restrict__ Cout1,
              int M, int N, int K, int TCa, int bstride, int row0, int ldT) {
  const unsigned short* BT = blockIdx.z ? BT1 : BT0;
  const float* bias = blockIdx.z ? bias1 : bias0;
  void* Cout = blockIdx.z ? Cout1 : Cout0;
  __shared__ __align__(16) unsigned short smem[2 * 128 * 32];  // 16KB
  unsigned short* As = smem;
  unsigned short* Bs = smem + 128 * 32;
  const int m0 = blockIdx.y * 128, n0 = blockIdx.x * 128;
  const int tid = threadIdx.x;
  const int lane = tid & 63, wave = tid >> 6;
  const int wm = (wave >> 1) * 64, wn = (wave & 1) * 64;
  const int l16 = lane & 15, quad = lane >> 4;
  const int sr = tid >> 2;
  const int sc = (((tid & 3) ^ ((tid >> 3) & 3))) * 8;
  const int pch = (quad ^ ((l16 >> 1) & 3)) * 8;

  floatx4 acc[4][4] = {};

  const int mA0 = m0 + sr, mA1 = m0 + sr + 64;
  const int gA0 = (mA0 / TCa) * bstride + row0 + (mA0 % TCa);
  const int gA1 = (mA1 / TCa) * bstride + row0 + (mA1 % TCa);
  const unsigned short* Arow0 = A + (size_t)gA0 * K + sc;
  const unsigned short* Arow1 = A + (size_t)gA1 * K + sc;
  const unsigned short* Brow0 = BT + (size_t)(n0 + sr) * K + sc;
  const unsigned short* Brow1 = BT + (size_t)(n0 + sr + 64) * K + sc;
  unsigned short* ldsA0 = As + (wave * 16) * 32;
  unsigned short* ldsA1 = As + (64 + wave * 16) * 32;
  unsigned short* ldsB0 = Bs + (wave * 16) * 32;
  unsigned short* ldsB1 = Bs + (64 + wave * 16) * 32;

  for (int k0 = 0; k0 < K; k0 += 32) {
    async_cp16(Arow0 + k0, ldsA0);
    async_cp16(Arow1 + k0, ldsA1);
    async_cp16(Brow0 + k0, ldsB0);
    async_cp16(Brow1 + k0, ldsB1);
    __syncthreads();
    half8 af[4], bf[4];
#pragma unroll
    for (int i = 0; i < 4; i++) {
      af[i] = __builtin_bit_cast(half8, *(const uint4*)&As[(wm + i * 16 + l16) * 32 + pch]);
      bf[i] = __builtin_bit_cast(half8, *(const uint4*)&Bs[(wn + i * 16 + l16) * 32 + pch]);
    }
#pragma unroll
    for (int mi = 0; mi < 4; mi++)
#pragma unroll
      for (int ni = 0; ni < 4; ni++)
        acc[mi][ni] = __builtin_amdgcn_mfma_f32_16x16x32_f16(af[mi], bf[ni], acc[mi][ni], 0, 0, 0);
    __syncthreads();
  }

  // C/D layout: col = lane&15, row(t) = (lane>>4)*4 + reg
  if (TRANS) {
#pragma unroll
    for (int ph = 0; ph < 2; ph++) {
      __syncthreads();
#pragma unroll
      for (int nn = 0; nn < 2; nn++) {
        int ni = ph * 2 + nn;
        int colb = wn + ni * 16 + l16;
        int cc = (wn >> 1) + nn * 16 + l16;
        float bv = bias[n0 + colb];
#pragma unroll
        for (int mi = 0; mi < 4; mi++) {
          int slot = (wm >> 2) + mi * 4 + quad;
          int pair = slot >> 1, bitb = slot & 1;
          int phys = ((pair ^ (cc & 15)) << 1) | bitb;
          union { _Float16 h[4]; unsigned long long u; } pk;
#pragma unroll
          for (int r = 0; r < 4; r++) {
            float v = acc[mi][ni][r] + bv;
            if (ACT == 1) v = softplus_f(v);
            pk.h[r] = (_Float16)v;
          }
          *(unsigned long long*)&smem[cc * 128 + phys * 4] = pk.u;
        }
      }
      __syncthreads();
#pragma unroll
      for (int pass = 0; pass < 4; pass++) {
        int cc = (tid >> 4) + pass * 16;
        int p16 = tid & 15;
        uint4 v = *(const uint4*)&smem[cc * 128 + (p16 ^ (cc & 15)) * 8];
        int colb = ((cc & 32) ? 64 : 0) + (ph * 2 + ((cc >> 4) & 1)) * 16 + (cc & 15);
        *(uint4*)&((unsigned short*)Cout)[(size_t)(n0 + colb) * ldT + m0 + p16 * 8] = v;
      }
    }
  } else {
#pragma unroll
    for (int ni = 0; ni < 4; ni++) {
      int col = n0 + wn + ni * 16 + l16;
      float bv = bias[col];
#pragma unroll
      for (int mi = 0; mi < 4; mi++) {
#pragma unroll
        for (int r = 0; r < 4; r++) {
          int row = m0 + wm + mi * 16 + quad * 4 + r;
          float v = acc[mi][ni][r] + bv;
          if (ACT == 1) v = softplus_f(v);
          if (OUTH) ((unsigned short*)Cout)[(size_t)row * N + col] = f2h(v);
          else      ((float*)Cout)[(size_t)row * N + col] = v;
        }
      }
    }
  }
}

// depthwise causal conv K=4 over u (= uv[:, :768]); 2 channels/thread
__global__ void dwconv(const unsigned short* __restrict__ uv,
                       const float* __restrict__ Wconv,
                       const float* __restrict__ bconv,
                       unsigned short* __restrict__ uc) {
  int idx = blockIdx.x * 256 + threadIdx.x;
  int c = (idx % (DM / 2)) * 2;
  int row = idx / (DM / 2);
  int t = row & (SEQ - 1);
  float a0 = bconv[c], a1 = bconv[c + 1];
  const float* w0 = Wconv + c * 4;
  const float* w1 = Wconv + (c + 1) * 4;
#pragma unroll
  for (int k = 0; k < 4; k++) {
    int tt = t - 3 + k;
    if (tt >= 0) {
      ushort2 u2 = *(const ushort2*)&uv[(size_t)(row - 3 + k) * N_UV + c];
      a0 += h2f(u2.x) * w0[k];
      a1 += h2f(u2.y) * w1[k];
    }
  }
  ushort2 o; o.x = f2h(a0); o.y = f2h(a1);
  *(ushort2*)&uc[(size_t)row * DM + c] = o;
}

// ---- time-parallel scan; transposed streams, FULL-LINE (128B) per-lane groups ----
// lane = ch*16 + j over 4 channels; grid (NGRP, SUBn); TSUB = TC/SUBn, %64==0.
// Per 64-step group each lane loads 8 contiguous uint4 per stream (one full
// 128B line) into registers, then runs the recurrence from registers.
__global__ __launch_bounds__(64)
void scan_pass1(const unsigned short* __restrict__ dtT,   // [DM][MR8]
                const unsigned short* __restrict__ ucT,   // [DM][MR8]
                const unsigned short* __restrict__ BtcT,  // [N_BC][MC8]
                const float* __restrict__ A_log,
                float* __restrict__ Ssub, float* __restrict__ Aexp,
                int ci, int TC, int SUBn, int MC8) {
  const int TSUB = TC / SUBn;
  int wid = blockIdx.x, sub = blockIdx.y;
  int b = wid / (DM / 4);
  int c0 = (wid % (DM / 4)) * 4;
  int lane = threadIdx.x;
  int c = c0 + (lane >> 4);
  float Acj = -__expf(A_log[c0 * DS + lane]);
  int col = c0 * DS + lane;
  size_t gbase = (size_t)b * SEQ + (size_t)ci * TC + (size_t)sub * TSUB;
  size_t lbase = (size_t)b * TC + (size_t)sub * TSUB;
  const unsigned short* pB = BtcT + (size_t)col * MC8 + lbase;
  const unsigned short* pD = dtT + (size_t)c * MR8 + gbase;
  const unsigned short* pU = ucT + (size_t)c * MR8 + gbase;

  float s = 0.f, dsum = 0.f;
  for (int t0 = 0; t0 < TSUB; t0 += 64) {
    uint4 B4[8], D4[8], U4[8];
#pragma unroll
    for (int q = 0; q < 8; q++) {
      B4[q] = *(const uint4*)(pB + t0 + q * 8);
      D4[q] = *(const uint4*)(pD + t0 + q * 8);
      U4[q] = *(const uint4*)(pU + t0 + q * 8);
    }
#pragma unroll
    for (int q = 0; q < 8; q++) {
      half8 hB = __builtin_bit_cast(half8, B4[q]);
      half8 hD = __builtin_bit_cast(half8, D4[q]);
      half8 hU = __builtin_bit_cast(half8, U4[q]);
#pragma unroll
      for (int i = 0; i < 8; i++) {
        float dtc = (float)hD[i];
        dsum += dtc;
        s = fmaf(s, __expf(dtc * Acj), dtc * (float)hB[i] * (float)hU[i]);
      }
    }
  }
  int idx = (sub * BATCH + b) * N_BC + col;
  Ssub[idx] = s;
  Aexp[idx] = __expf(Acj * dsum);
}

// chain sub-chunk transitions; carry s_state across NC-chunks
__global__ __launch_bounds__(64)
void scan_combine(const float* __restrict__ Ssub, const float* __restrict__ Aexp,
                  float* __restrict__ Sinit, float* __restrict__ s_state,
                  int ci, int SUBn) {
  int wid = blockIdx.x;
  int b = wid / (DM / 4);
  int c0 = (wid % (DM / 4)) * 4;
  int col = c0 * DS + threadIdx.x;
  int sidx = b * N_BC + col;
  float s = (ci == 0) ? 0.f : s_state[sidx];
  for (int k = 0; k < SUBn; k++) {
    int idx = (k * BATCH + b) * N_BC + col;
    Sinit[idx] = s;
    s = fmaf(s, Aexp[idx], Ssub[idx]);
  }
  s_state[sidx] = s;
}

// Pass 2: rerun recurrence from Sinit, emit gated yg (row-major fp16)
__global__ __launch_bounds__(64)
void scan_pass2(const unsigned short* __restrict__ dtT,
                const unsigned short* __restrict__ ucT,
                const unsigned short* __restrict__ BtcT,
                const unsigned short* __restrict__ CtcT,
                const unsigned short* __restrict__ vT,
                const float* __restrict__ A_log,
                const float* __restrict__ Dv,
                const float* __restrict__ Sinit,
                unsigned short* __restrict__ yg,
                int ci, int TC, int SUBn, int MC8) {
  const int TSUB = TC / SUBn;
  int wid = blockIdx.x, sub = blockIdx.y;
  int b = wid / (DM / 4);
  int c0 = (wid % (DM / 4)) * 4;
  int lane = threadIdx.x;
  int j = lane & 15;
  int c = c0 + (lane >> 4);
  float Acj = -__expf(A_log[c0 * DS + lane]);
  float Dc = Dv[c];
  int col = c0 * DS + lane;
  float s = Sinit[(sub * BATCH + b) * N_BC + col];
  size_t gbase = (size_t)b * SEQ + (size_t)ci * TC + (size_t)sub * TSUB;
  size_t lbase = (size_t)b * TC + (size_t)sub * TSUB;
  const unsigned short* pB = BtcT + (size_t)col * MC8 + lbase;
  const unsigned short* pC = CtcT + (size_t)col * MC8 + lbase;
  const unsigned short* pD = dtT + (size_t)c * MR8 + gbase;
  const unsigned short* pU = ucT + (size_t)c * MR8 + gbase;
  const unsigned short* pV = vT + (size_t)c * MR8 + gbase;

  for (int t0 = 0; t0 < TSUB; t0 += 64) {
    uint4 B4[8], C4[8], D4[8], U4[8], V4[8];
#pragma unroll
    for (int q = 0; q < 8; q++) {
      B4[q] = *(const uint4*)(pB + t0 + q * 8);
      C4[q] = *(const uint4*)(pC + t0 + q * 8);
      D4[q] = *(const uint4*)(pD + t0 + q * 8);
      U4[q] = *(const uint4*)(pU + t0 + q * 8);
      V4[q] = *(const uint4*)(pV + t0 + q * 8);
    }
#pragma unroll
    for (int q = 0; q < 8; q++) {
      half8 hB = __builtin_bit_cast(half8, B4[q]);
      half8 hC = __builtin_bit_cast(half8, C4[q]);
      half8 hD = __builtin_bit_cast(half8, D4[q]);
      half8 hU = __builtin_bit_cast(half8, U4[q]);
      half8 hV = __builtin_bit_cast(half8, V4[q]);
#pragma unroll
      for (int i = 0; i < 8; i++) {
        float dtc = (float)hD[i];
        float uu = (float)hU[i];
        s = fmaf(s, __expf(dtc * Acj), dtc * (float)hB[i] * uu);
        float yt = row_reduce16((float)hC[i] * s);
        if (j == 0) {
          float y = yt + Dc * uu;
          float g = 1.f / (1.f + __expf(-(float)hV[i]));
          yg[(gbase + t0 + q * 8 + i) * DM + c] = f2h(y * g);
        }
      }
    }
  }
}

extern "C" void kernel_launch(void* const* d_in, const int* in_sizes, int n_in,
                              void* d_out, int out_size, void* d_ws, size_t ws_size,
                              hipStream_t stream) {
  const float* x     = (const float*)d_in[0];
  const float* Wi    = (const float*)d_in[1];
  const float* bi    = (const float*)d_in[2];
  const float* Wconv = (const float*)d_in[3];
  const float* bconv = (const float*)d_in[4];
  const float* Wdt   = (const float*)d_in[5];
  const float* bdt   = (const float*)d_in[6];
  const float* WB    = (const float*)d_in[7];
  const float* bB    = (const float*)d_in[8];
  const float* WC    = (const float*)d_in[9];
  const float* bC    = (const float*)d_in[10];
  const float* A_log = (const float*)d_in[11];
  const float* Dv    = (const float*)d_in[12];
  const float* Wo    = (const float*)d_in[13];
  const float* bo    = (const float*)d_in[14];
  float* out = (float*)d_out;
  (void)in_sizes; (void)n_in; (void)out_size;

  auto pad = [](size_t b) { return (b + 255) & ~(size_t)255; };

  const size_t sz_xb   = pad((size_t)MROWS * DM * 2);      // reused as yg
  const size_t sz_WiT  = pad((size_t)N_UV * DM * 2);
  const size_t sz_WdtT = pad((size_t)DM * DM * 2);
  const size_t sz_WBT  = pad((size_t)N_BC * DM * 2);
  const size_t sz_WCT  = pad((size_t)N_BC * DM * 2);
  const size_t sz_WoT  = pad((size_t)DM * DM * 2);
  const size_t sz_uvb  = pad((size_t)MROWS * N_UV * 2);
  const size_t sz_ucb  = pad((size_t)MROWS * DM * 2);
  const size_t sz_tr   = pad((size_t)DM * MR8 * 2);        // dtT / ucT / vT each
  const size_t sz_st   = pad((size_t)BATCH * N_BC * 4);
  const size_t sz_sub  = pad((size_t)SUBMAX * BATCH * N_BC * 4);
  const size_t fixed = sz_xb + sz_WiT + sz_WdtT + sz_WBT + sz_WCT + sz_WoT +
                       sz_uvb + sz_ucb + 3 * sz_tr + sz_st + 3 * sz_sub;

  int NC = 16;
  for (int nc : {1, 2, 4, 8, 16}) {
    size_t need = fixed + 2 * pad((size_t)N_BC * (BATCH * (SEQ / nc) + 8) * 2);
    if (need <= ws_size) { NC = nc; break; }
  }
  const int TC = SEQ / NC;       // 2048/NC; TC/64 = SUBn >= 2
  const int MC = BATCH * TC;
  const int MC8 = MC + 8;
  const int SUBn = TC / 64;      // TSUB = 64 exactly

  char* ws = (char*)d_ws;
  size_t off = 0;
  auto alloc = [&](size_t bytes) { char* p = ws + off; off += bytes; return p; };
  unsigned short* xb   = (unsigned short*)alloc(sz_xb);
  unsigned short* WiT  = (unsigned short*)alloc(sz_WiT);
  unsigned short* WdtT = (unsigned short*)alloc(sz_WdtT);
  unsigned short* WBT  = (unsigned short*)alloc(sz_WBT);
  unsigned short* WCT  = (unsigned short*)alloc(sz_WCT);
  unsigned short* WoT  = (unsigned short*)alloc(sz_WoT);
  unsigned short* uvb  = (unsigned short*)alloc(sz_uvb);
  unsigned short* ucb  = (unsigned short*)alloc(sz_ucb);
  unsigned short* dtT  = (unsigned short*)alloc(sz_tr);
  unsigned short* ucT  = (unsigned short*)alloc(sz_tr);
  unsigned short* vT   = (unsigned short*)alloc(sz_tr);
  float*          sst  = (float*)alloc(sz_st);
  float*          Ssub = (float*)alloc(sz_sub);
  float*          Aexp = (float*)alloc(sz_sub);
  float*          Sini = (float*)alloc(sz_sub);
  unsigned short* Btc  = (unsigned short*)alloc(pad((size_t)N_BC * MC8 * 2));
  unsigned short* Ctc  = (unsigned short*)alloc(pad((size_t)N_BC * MC8 * 2));
  unsigned short* ygb  = xb;

  convert_f2h<<<dim3(MROWS * DM / 1024), dim3(256), 0, stream>>>(x, xb, MROWS * DM);
  transpose_w5<<<dim3(N_BC / 32, DM / 32, 5), dim3(32, 8), 0, stream>>>(
      Wi, Wdt, WB, WC, Wo, WiT, WdtT, WBT, WCT, WoT, N_UV, DM, N_BC, N_BC, DM);

  // uv = x @ Wi + bi   (fp16, row-major)
  gemm_f16<0, 1, 0><<<dim3(N_UV / 128, MROWS / 128, 1), 256, 0, stream>>>(
      xb, WiT, WiT, bi, bi, uvb, uvb, MROWS, N_UV, DM, MROWS, 0, 0, 0);
  dwconv<<<dim3(MROWS * DM / 512), 256, 0, stream>>>(uvb, Wconv, bconv, ucb);
  // ucT, vT (transposed copies for the scan)
  transpose_h<<<dim3(MROWS / 64, DM / 64), 256, 0, stream>>>(ucb, DM, ucT, MR8);
  transpose_h<<<dim3(MROWS / 64, DM / 64), 256, 0, stream>>>(uvb + DM, N_UV, vT, MR8);
  // dtT = softplus(u_conv @ Wdt + bdt)^T  ([DM][MR8], fp16)
  gemm_f16<1, 1, 1><<<dim3(DM / 128, MROWS / 128, 1), 256, 0, stream>>>(
      ucb, WdtT, WdtT, bdt, bdt, dtT, dtT, MROWS, DM, DM, MROWS, 0, 0, MR8);

  for (int ci = 0; ci < NC; ci++) {
    gemm_f16<0, 1, 1><<<dim3(N_BC / 128, MC / 128, 2), 256, 0, stream>>>(
        ucb, WBT, WCT, bB, bC, Btc, Ctc, MC, N_BC, DM, TC, SEQ, ci * TC, MC8);
    scan_pass1<<<dim3(NGRP, SUBn), 64, 0, stream>>>(dtT, ucT, Btc, A_log,
                                                    Ssub, Aexp, ci, TC, SUBn, MC8);
    scan_combine<<<dim3(NGRP), 64, 0, stream>>>(Ssub, Aexp, Sini, sst, ci, SUBn);
    scan_pass2<<<dim3(NGRP, SUBn), 64, 0, stream>>>(dtT, ucT, Btc, Ctc, vT,
                                                    A_log, Dv, Sini, ygb, ci, TC, SUBn, MC8);
  }

  // out = yg @ Wo + bo  (fp32, row-major)
  gemm_f16<0, 0, 0><<<dim3(DM / 128, MROWS / 128, 1), 256, 0, stream>>>(
      ygb, WoT, WoT, bo, bo, out, out, MROWS, DM, DM, MROWS, 0, 0, 0);
}

// Round 8
// 599.562 us; speedup vs baseline: 1.1831x; 1.1831x over previous
//
#include <hip/hip_runtime.h>

#define DM 768
#define DS 16
#define SEQ 2048
#define BATCH 2
#define MROWS (BATCH*SEQ)   // 4096
#define N_UV (2*DM)         // 1536
#define N_BC (DM*DS)        // 12288
#define NGRP (BATCH*DM/4)   // 384 scan wave-groups
#define SUBMAX 64

typedef _Float16 half8 __attribute__((ext_vector_type(8)));
typedef float floatx4 __attribute__((ext_vector_type(4)));

static __device__ __forceinline__ unsigned short f2h(float f) {
  _Float16 h = (_Float16)f;
  return __builtin_bit_cast(unsigned short, h);
}
static __device__ __forceinline__ float h2f(unsigned short u) {
  return (float)__builtin_bit_cast(_Float16, u);
}
static __device__ __forceinline__ float softplus_f(float x) {
  return (x > 20.f) ? x : log1pf(__expf(x));
}
// async global->LDS, 16B per lane; LDS dest = l + lane*16 (l wave-uniform)
static __device__ __forceinline__ void async_cp16(const unsigned short* g,
                                                  unsigned short* l) {
  __builtin_amdgcn_global_load_lds(
      (const __attribute__((address_space(1))) void*)g,
      (__attribute__((address_space(3))) void*)l, 16, 0, 0);
}
// sum across each 16-lane row via DPP row_ror (pure VALU, no LDS pipe)
static __device__ __forceinline__ float row_reduce16(float v) {
  int x;
  x = __builtin_amdgcn_update_dpp(0, __builtin_bit_cast(int, v), 0x128, 0xf, 0xf, true);
  v += __builtin_bit_cast(float, x);
  x = __builtin_amdgcn_update_dpp(0, __builtin_bit_cast(int, v), 0x124, 0xf, 0xf, true);
  v += __builtin_bit_cast(float, x);
  x = __builtin_amdgcn_update_dpp(0, __builtin_bit_cast(int, v), 0x122, 0xf, 0xf, true);
  v += __builtin_bit_cast(float, x);
  x = __builtin_amdgcn_update_dpp(0, __builtin_bit_cast(int, v), 0x121, 0xf, 0xf, true);
  v += __builtin_bit_cast(float, x);
  return v;
}

// elementwise fp32 -> fp16 ; n divisible by 1024
__global__ void convert_f2h(const float* __restrict__ in,
                            unsigned short* __restrict__ out, int n) {
  int i = (blockIdx.x * blockDim.x + threadIdx.x) * 4;
  if (i >= n) return;
  float4 f = *(const float4*)(in + i);
  ushort4 h;
  h.x = f2h(f.x); h.y = f2h(f.y); h.z = f2h(f.z); h.w = f2h(f.w);
  *(ushort4*)(out + i) = h;
}

// All 5 weight transposes in one launch (z selects). W [768][N] f32 -> WT [N][768] f16.
__global__ void transpose_w5(const float* __restrict__ W0, const float* __restrict__ W1,
                             const float* __restrict__ W2, const float* __restrict__ W3,
                             const float* __restrict__ W4,
                             unsigned short* __restrict__ T0, unsigned short* __restrict__ T1,
                             unsigned short* __restrict__ T2, unsigned short* __restrict__ T3,
                             unsigned short* __restrict__ T4,
                             int N0, int N1, int N2, int N3, int N4) {
  const float* W; unsigned short* WT; int N;
  switch (blockIdx.z) {
    case 0: W = W0; WT = T0; N = N0; break;
    case 1: W = W1; WT = T1; N = N1; break;
    case 2: W = W2; WT = T2; N = N2; break;
    case 3: W = W3; WT = T3; N = N3; break;
    default: W = W4; WT = T4; N = N4; break;
  }
  int n0 = blockIdx.x * 32;
  if (n0 >= N) return;
  int k0 = blockIdx.y * 32;
  __shared__ float tile[32][33];
  int tx = threadIdx.x, ty = threadIdx.y;   // (32,8)
#pragma unroll
  for (int i = 0; i < 32; i += 8)
    tile[ty + i][tx] = W[(size_t)(k0 + ty + i) * N + (n0 + tx)];
  __syncthreads();
  int kp = tx & 15, half = tx >> 4;
#pragma unroll
  for (int i = 0; i < 2; i++) {
    int nl = ty + half * 8 + i * 16;
    unsigned int pk = (unsigned int)f2h(tile[2 * kp][nl]) |
                      ((unsigned int)f2h(tile[2 * kp + 1][nl]) << 16);
    *(unsigned int*)&WT[(size_t)(n0 + nl) * DM + k0 + 2 * kp] = pk;
  }
}

// C[M][N] = A[g(M)][K] @ BT[N][K]^T + bias ; ACT=1 -> softplus ; OUTH=1 -> fp16
// A-row remap g(m) = (m/TCa)*bstride + row0 + (m%TCa). gridDim.z picks the
// (BT,bias,out) set. 128x128 tile, BK=32, global_load_lds width-16 staging
// into XOR-swizzled [128][32] LDS (chunk q of row r at q ^ ((r>>1)&3)).
template<int ACT, int OUTH>
__global__ __launch_bounds__(256)
void gemm_f16(const unsigned short* __restrict__ A,
              const unsigned short* __restrict__ BT0,
              const unsigned short* __restrict__ BT1,
              const float* __restrict__ bias0,
              const float* __restrict__ bias1,
              void* __restrict__ Cout0,
              void* __restrict__ Cout1,
              int M, int N, int K, int TCa, int bstride, int row0) {
  const unsigned short* BT = blockIdx.z ? BT1 : BT0;
  const float* bias = blockIdx.z ? bias1 : bias0;
  void* Cout = blockIdx.z ? Cout1 : Cout0;
  __shared__ __align__(16) unsigned short As[128 * 32];
  __shared__ __align__(16) unsigned short Bs[128 * 32];
  const int m0 = blockIdx.y * 128, n0 = blockIdx.x * 128;
  const int tid = threadIdx.x;
  const int lane = tid & 63, wave = tid >> 6;
  const int wm = (wave >> 1) * 64, wn = (wave & 1) * 64;
  const int l16 = lane & 15, quad = lane >> 4;
  const int sr = tid >> 2;                               // staging row 0..63
  const int sc = (((tid & 3) ^ ((tid >> 3) & 3))) * 8;   // swizzled src chunk
  const int pch = (quad ^ ((l16 >> 1) & 3)) * 8;         // swizzled read chunk

  floatx4 acc[4][4] = {};

  const int mA0 = m0 + sr, mA1 = m0 + sr + 64;
  const int gA0 = (mA0 / TCa) * bstride + row0 + (mA0 % TCa);
  const int gA1 = (mA1 / TCa) * bstride + row0 + (mA1 % TCa);
  const unsigned short* Arow0 = A + (size_t)gA0 * K + sc;
  const unsigned short* Arow1 = A + (size_t)gA1 * K + sc;
  const unsigned short* Brow0 = BT + (size_t)(n0 + sr) * K + sc;
  const unsigned short* Brow1 = BT + (size_t)(n0 + sr + 64) * K + sc;
  unsigned short* ldsA0 = As + (wave * 16) * 32;
  unsigned short* ldsA1 = As + (64 + wave * 16) * 32;
  unsigned short* ldsB0 = Bs + (wave * 16) * 32;
  unsigned short* ldsB1 = Bs + (64 + wave * 16) * 32;

  for (int k0 = 0; k0 < K; k0 += 32) {
    async_cp16(Arow0 + k0, ldsA0);
    async_cp16(Arow1 + k0, ldsA1);
    async_cp16(Brow0 + k0, ldsB0);
    async_cp16(Brow1 + k0, ldsB1);
    __syncthreads();
    half8 af[4], bf[4];
#pragma unroll
    for (int i = 0; i < 4; i++) {
      af[i] = __builtin_bit_cast(half8, *(const uint4*)&As[(wm + i * 16 + l16) * 32 + pch]);
      bf[i] = __builtin_bit_cast(half8, *(const uint4*)&Bs[(wn + i * 16 + l16) * 32 + pch]);
    }
#pragma unroll
    for (int mi = 0; mi < 4; mi++)
#pragma unroll
      for (int ni = 0; ni < 4; ni++)
        acc[mi][ni] = __builtin_amdgcn_mfma_f32_16x16x32_f16(af[mi], bf[ni], acc[mi][ni], 0, 0, 0);
    __syncthreads();
  }

  // C/D layout: col = lane&15, row = (lane>>4)*4 + reg
#pragma unroll
  for (int ni = 0; ni < 4; ni++) {
    int col = n0 + wn + ni * 16 + l16;
    float bv = bias[col];
#pragma unroll
    for (int mi = 0; mi < 4; mi++) {
#pragma unroll
      for (int r = 0; r < 4; r++) {
        int row = m0 + wm + mi * 16 + quad * 4 + r;
        float v = acc[mi][ni][r] + bv;
        if (ACT == 1) v = softplus_f(v);
        if (OUTH) ((unsigned short*)Cout)[(size_t)row * N + col] = f2h(v);
        else      ((float*)Cout)[(size_t)row * N + col] = v;
      }
    }
  }
}

// depthwise causal conv K=4 over u (= uv[:, :768]); 2 channels/thread
__global__ void dwconv(const unsigned short* __restrict__ uv,
                       const float* __restrict__ Wconv,   // [768][4]
                       const float* __restrict__ bconv,
                       unsigned short* __restrict__ uc) {
  int idx = blockIdx.x * 256 + threadIdx.x;   // over MROWS*DM/2
  int c = (idx % (DM / 2)) * 2;
  int row = idx / (DM / 2);
  int t = row & (SEQ - 1);
  float a0 = bconv[c], a1 = bconv[c + 1];
  const float* w0 = Wconv + c * 4;
  const float* w1 = Wconv + (c + 1) * 4;
#pragma unroll
  for (int k = 0; k < 4; k++) {
    int tt = t - 3 + k;
    if (tt >= 0) {
      ushort2 u2 = *(const ushort2*)&uv[(size_t)(row - 3 + k) * N_UV + c];
      a0 += h2f(u2.x) * w0[k];
      a1 += h2f(u2.y) * w1[k];
    }
  }
  ushort2 o; o.x = f2h(a0); o.y = f2h(a1);
  *(ushort2*)&uc[(size_t)row * DM + c] = o;
}

// ---- time-parallel scan over one NC-chunk (row-major streams, R4 structure) ----
// lane = ch*16 + j over 4 channels; grid (NGRP, SUBn); TSUB = TC/SUBn (>=8, %8==0).
__global__ __launch_bounds__(64)
void scan_pass1(const unsigned short* __restrict__ dt,   // fp16 [MROWS][DM]
                const unsigned short* __restrict__ uc,
                const unsigned short* __restrict__ Btc,  // [BATCH*TC][N_BC]
                const float* __restrict__ A_log,
                float* __restrict__ Ssub,                // [SUBn][BATCH][N_BC]
                float* __restrict__ Aexp,
                int ci, int TC, int SUBn) {
  const int TSUB = TC / SUBn;
  int wid = blockIdx.x, sub = blockIdx.y;
  int b = wid / (DM / 4);
  int c0 = (wid % (DM / 4)) * 4;
  int lane = threadIdx.x;
  int c = c0 + (lane >> 4);
  float Acj = -__expf(A_log[c0 * DS + lane]);
  int col = c0 * DS + lane;
  size_t gbase = (size_t)b * SEQ + (size_t)ci * TC + (size_t)sub * TSUB;
  size_t lbase = (size_t)b * TC + (size_t)sub * TSUB;

  float s = 0.f, dsum = 0.f;
  float n_dt[8], n_u[8], n_B[8];
#pragma unroll
  for (int i = 0; i < 8; i++) {
    n_dt[i] = h2f(dt[(gbase + i) * DM + c]);
    n_u[i]  = h2f(uc[(gbase + i) * DM + c]);
    n_B[i]  = h2f(Btc[(lbase + i) * N_BC + col]);
  }
  for (int t0 = 0; t0 < TSUB; t0 += 8) {
    float c_dt[8], c_u[8], c_B[8];
#pragma unroll
    for (int i = 0; i < 8; i++) { c_dt[i] = n_dt[i]; c_u[i] = n_u[i]; c_B[i] = n_B[i]; }
    if (t0 + 8 < TSUB) {
#pragma unroll
      for (int i = 0; i < 8; i++) {
        size_t gr = gbase + t0 + 8 + i, lr = lbase + t0 + 8 + i;
        n_dt[i] = h2f(dt[gr * DM + c]);
        n_u[i]  = h2f(uc[gr * DM + c]);
        n_B[i]  = h2f(Btc[lr * N_BC + col]);
      }
    }
#pragma unroll
    for (int i = 0; i < 8; i++) {
      float dtc = c_dt[i];
      dsum += dtc;
      float a = __expf(dtc * Acj);
      s = fmaf(s, a, dtc * c_B[i] * c_u[i]);
    }
  }
  int idx = (sub * BATCH + b) * N_BC + col;
  Ssub[idx] = s;
  Aexp[idx] = __expf(Acj * dsum);
}

// chain sub-chunk transitions (register-prefetched); Sinit may alias Ssub
// (all loads complete before any store). Carries s_state across NC-chunks.
template<int SUBN>
__global__ __launch_bounds__(64)
void scan_combine(const float* Ssub, const float* Aexp,
                  float* Sinit, float* s_state, int ci) {
  int wid = blockIdx.x;
  int b = wid / (DM / 4);
  int c0 = (wid % (DM / 4)) * 4;
  int col = c0 * DS + threadIdx.x;
  int sidx = b * N_BC + col;
  float sa[SUBN], ae[SUBN];
#pragma unroll
  for (int k = 0; k < SUBN; k++) {
    int idx = (k * BATCH + b) * N_BC + col;
    sa[k] = Ssub[idx];
    ae[k] = Aexp[idx];
  }
  float s = (ci == 0) ? 0.f : s_state[sidx];
#pragma unroll
  for (int k = 0; k < SUBN; k++) {
    int idx = (k * BATCH + b) * N_BC + col;
    Sinit[idx] = s;
    s = fmaf(s, ae[k], sa[k]);
  }
  s_state[sidx] = s;
}

// Pass 2: rerun recurrence from Sinit, emit gated output yg (fp16, row-major)
__global__ __launch_bounds__(64)
void scan_pass2(const unsigned short* __restrict__ dt,
                const unsigned short* __restrict__ uc,
                const unsigned short* __restrict__ Btc,
                const unsigned short* __restrict__ Ctc,
                const unsigned short* __restrict__ uv,
                const float* __restrict__ A_log,
                const float* __restrict__ Dv,
                const float* __restrict__ Sinit,
                unsigned short* __restrict__ yg,
                int ci, int TC, int SUBn) {
  const int TSUB = TC / SUBn;
  int wid = blockIdx.x, sub = blockIdx.y;
  int b = wid / (DM / 4);
  int c0 = (wid % (DM / 4)) * 4;
  int lane = threadIdx.x;
  int j = lane & 15;
  int c = c0 + (lane >> 4);
  float Acj = -__expf(A_log[c0 * DS + lane]);
  float Dc = Dv[c];
  int col = c0 * DS + lane;
  float s = Sinit[(sub * BATCH + b) * N_BC + col];
  size_t gbase = (size_t)b * SEQ + (size_t)ci * TC + (size_t)sub * TSUB;
  size_t lbase = (size_t)b * TC + (size_t)sub * TSUB;

  float n_dt[8], n_u[8], n_B[8], n_C[8], n_v[8];
#pragma unroll
  for (int i = 0; i < 8; i++) {
    size_t gr = gbase + i, lr = lbase + i;
    n_dt[i] = h2f(dt[gr * DM + c]);
    n_u[i]  = h2f(uc[gr * DM + c]);
    n_B[i]  = h2f(Btc[lr * N_BC + col]);
    n_C[i]  = h2f(Ctc[lr * N_BC + col]);
    n_v[i]  = h2f(uv[gr * N_UV + DM + c]);
  }
  for (int t0 = 0; t0 < TSUB; t0 += 8) {
    float c_dt[8], c_u[8], c_B[8], c_C[8], c_v[8];
#pragma unroll
    for (int i = 0; i < 8; i++) {
      c_dt[i] = n_dt[i]; c_u[i] = n_u[i]; c_B[i] = n_B[i];
      c_C[i] = n_C[i]; c_v[i] = n_v[i];
    }
    if (t0 + 8 < TSUB) {
#pragma unroll
      for (int i = 0; i < 8; i++) {
        size_t gr = gbase + t0 + 8 + i, lr = lbase + t0 + 8 + i;
        n_dt[i] = h2f(dt[gr * DM + c]);
        n_u[i]  = h2f(uc[gr * DM + c]);
        n_B[i]  = h2f(Btc[lr * N_BC + col]);
        n_C[i]  = h2f(Ctc[lr * N_BC + col]);
        n_v[i]  = h2f(uv[gr * N_UV + DM + c]);
      }
    }
#pragma unroll
    for (int i = 0; i < 8; i++) {
      float dtc = c_dt[i];
      float a = __expf(dtc * Acj);
      s = fmaf(s, a, dtc * c_B[i] * c_u[i]);
      float yt = row_reduce16(c_C[i] * s);
      if (j == 0) {
        float y = yt + Dc * c_u[i];
        float g = 1.f / (1.f + __expf(-c_v[i]));
        yg[(gbase + t0 + i) * DM + c] = f2h(y * g);
      }
    }
  }
}

extern "C" void kernel_launch(void* const* d_in, const int* in_sizes, int n_in,
                              void* d_out, int out_size, void* d_ws, size_t ws_size,
                              hipStream_t stream) {
  const float* x     = (const float*)d_in[0];
  const float* Wi    = (const float*)d_in[1];
  const float* bi    = (const float*)d_in[2];
  const float* Wconv = (const float*)d_in[3];
  const float* bconv = (const float*)d_in[4];
  const float* Wdt   = (const float*)d_in[5];
  const float* bdt   = (const float*)d_in[6];
  const float* WB    = (const float*)d_in[7];
  const float* bB    = (const float*)d_in[8];
  const float* WC    = (const float*)d_in[9];
  const float* bC    = (const float*)d_in[10];
  const float* A_log = (const float*)d_in[11];
  const float* Dv    = (const float*)d_in[12];
  const float* Wo    = (const float*)d_in[13];
  const float* bo    = (const float*)d_in[14];
  float* out = (float*)d_out;
  (void)in_sizes; (void)n_in; (void)out_size;

  auto pad = [](size_t b) { return (b + 255) & ~(size_t)255; };

  const size_t sz_xb   = pad((size_t)MROWS * DM * 2);      // reused as yg
  const size_t sz_WiT  = pad((size_t)N_UV * DM * 2);
  const size_t sz_WdtT = pad((size_t)DM * DM * 2);
  const size_t sz_WBT  = pad((size_t)N_BC * DM * 2);
  const size_t sz_WCT  = pad((size_t)N_BC * DM * 2);
  const size_t sz_WoT  = pad((size_t)DM * DM * 2);
  const size_t sz_uvb  = pad((size_t)MROWS * N_UV * 2);
  const size_t sz_ucb  = pad((size_t)MROWS * DM * 2);
  const size_t sz_dtb  = pad((size_t)MROWS * DM * 2);
  const size_t sz_st   = pad((size_t)BATCH * N_BC * 4);
  const size_t sz_sub  = pad((size_t)SUBMAX * BATCH * N_BC * 4);  // Ssub(=Sinit)/Aexp
  const size_t fixed = sz_xb + sz_WiT + sz_WdtT + sz_WBT + sz_WCT + sz_WoT +
                       sz_uvb + sz_ucb + sz_dtb + sz_st + 2 * sz_sub;

  int NC = 16;
  for (int nc : {1, 2, 4, 8, 16}) {
    size_t need = fixed + 2 * pad((size_t)BATCH * (SEQ / nc) * N_BC * 2);
    if (need <= ws_size) { NC = nc; break; }
  }
  const int TC = SEQ / NC;
  const int MC = BATCH * TC;
  const int SUBn = (TC / 8 < SUBMAX) ? (TC / 8) : SUBMAX;   // 64/64/64/32/16

  char* ws = (char*)d_ws;
  size_t off = 0;
  auto alloc = [&](size_t bytes) { char* p = ws + off; off += bytes; return p; };
  unsigned short* xb   = (unsigned short*)alloc(sz_xb);
  unsigned short* WiT  = (unsigned short*)alloc(sz_WiT);
  unsigned short* WdtT = (unsigned short*)alloc(sz_WdtT);
  unsigned short* WBT  = (unsigned short*)alloc(sz_WBT);
  unsigned short* WCT  = (unsigned short*)alloc(sz_WCT);
  unsigned short* WoT  = (unsigned short*)alloc(sz_WoT);
  unsigned short* uvb  = (unsigned short*)alloc(sz_uvb);
  unsigned short* ucb  = (unsigned short*)alloc(sz_ucb);
  unsigned short* dtb  = (unsigned short*)alloc(sz_dtb);
  float*          sst  = (float*)alloc(sz_st);
  float*          Ssub = (float*)alloc(sz_sub);   // aliased as Sinit
  float*          Aexp = (float*)alloc(sz_sub);
  unsigned short* Btc  = (unsigned short*)alloc(pad((size_t)MC * N_BC * 2));
  unsigned short* Ctc  = (unsigned short*)alloc(pad((size_t)MC * N_BC * 2));
  unsigned short* ygb  = xb;   // x fp16 dead after the uv GEMM
  float*          Sini = Ssub; // combine preloads all Ssub before storing Sinit

  convert_f2h<<<dim3(MROWS * DM / 1024), dim3(256), 0, stream>>>(x, xb, MROWS * DM);
  transpose_w5<<<dim3(N_BC / 32, DM / 32, 5), dim3(32, 8), 0, stream>>>(
      Wi, Wdt, WB, WC, Wo, WiT, WdtT, WBT, WCT, WoT, N_UV, DM, N_BC, N_BC, DM);

  // uv = x @ Wi + bi   (fp16, row-major)
  gemm_f16<0, 1><<<dim3(N_UV / 128, MROWS / 128, 1), 256, 0, stream>>>(
      xb, WiT, WiT, bi, bi, uvb, uvb, MROWS, N_UV, DM, MROWS, 0, 0);
  dwconv<<<dim3(MROWS * DM / 512), 256, 0, stream>>>(uvb, Wconv, bconv, ucb);
  // dt = softplus(u_conv @ Wdt + bdt)  (fp16, row-major)
  gemm_f16<1, 1><<<dim3(DM / 128, MROWS / 128, 1), 256, 0, stream>>>(
      ucb, WdtT, WdtT, bdt, bdt, dtb, dtb, MROWS, DM, DM, MROWS, 0, 0);

  for (int ci = 0; ci < NC; ci++) {
    // Bt and Ct chunk GEMMs fused via gridDim.z (row-major out)
    gemm_f16<0, 1><<<dim3(N_BC / 128, MC / 128, 2), 256, 0, stream>>>(
        ucb, WBT, WCT, bB, bC, Btc, Ctc, MC, N_BC, DM, TC, SEQ, ci * TC);
    scan_pass1<<<dim3(NGRP, SUBn), 64, 0, stream>>>(dtb, ucb, Btc, A_log,
                                                    Ssub, Aexp, ci, TC, SUBn);
    switch (SUBn) {
      case 64: scan_combine<64><<<dim3(NGRP), 64, 0, stream>>>(Ssub, Aexp, Sini, sst, ci); break;
      case 32: scan_combine<32><<<dim3(NGRP), 64, 0, stream>>>(Ssub, Aexp, Sini, sst, ci); break;
      default: scan_combine<16><<<dim3(NGRP), 64, 0, stream>>>(Ssub, Aexp, Sini, sst, ci); break;
    }
    scan_pass2<<<dim3(NGRP, SUBn), 64, 0, stream>>>(dtb, ucb, Btc, Ctc, uvb,
                                                    A_log, Dv, Sini, ygb, ci, TC, SUBn);
  }

  // out = yg @ Wo + bo  (fp32, row-major)
  gemm_f16<0, 0><<<dim3(DM / 128, MROWS / 128, 1), 256, 0, stream>>>(
      ygb, WoT, WoT, bo, bo, out, out, MROWS, DM, DM, MROWS, 0, 0);
}